// Round 6
// baseline (238.752 us; speedup 1.0000x reference)
//
#include <hip/hip_runtime.h>

// Problem constants (match reference)
#define NBATCH   16
#define NUMATOM  512
#define NEIGH    48
#define NPAIR    (NUMATOM * NEIGH)        // 24576
#define TOTNATOM (NBATCH * NUMATOM)       // 8192
#define NTYPE    4
#define NWAVE    8
#define OUT_PER_ATOM 96                    // 4 types x 3 orders x 8 waves

// Partition for kernel 1
#define NQ      4                          // atom ranges per batch (128 atoms each)
#define NC      8                          // pair chunks per batch
#define RATOMS  (NUMATOM / NQ)             // 128
#define CHUNK   (NPAIR / NC)               // 3072
#define ASTRIDE 73                         // bank-spread pad (73 mod 32 = 9, coprime)
#define QCAP    1024                       // queue cap; E[kept]=768, sigma~24
#define PLANE   (RATOMS * 72)              // 9216 floats per partial plane

// ---------------------------------------------------------------------------
// Kernel 1: per-(batch, atom-range, pair-chunk) partial accumulation in LDS.
// No global atomics, no scattered global stores. Rows (j): 0..2 = ux,uy,uz;
// 3..5 = xx,yy,zz; 6..8 = xy,xz,yz (off-diagonals doubled at finalize).
// ---------------------------------------------------------------------------
__global__ __launch_bounds__(256, 2) void partial_accum(
        const float* __restrict__ coords,
        const int*   __restrict__ atom_index,
        const float* __restrict__ shifts,
        const int*   __restrict__ species,
        const float* __restrict__ rs,
        const float* __restrict__ inta,
        float*       __restrict__ part) {
    __shared__ float acc[RATOMS * ASTRIDE];   // 37,376 B
    __shared__ float lc[NUMATOM * 3];         //  6,144 B
    __shared__ int   lsp[RATOMS];             //    512 B
    __shared__ float lrs[NTYPE * NWAVE];      //    128 B
    __shared__ float lia[NTYPE * NWAVE];      //    128 B
    __shared__ int   queue[QCAP];             //  4,096 B
    __shared__ int   qn;

    int blk = blockIdx.x;
    int c   = blk % NC;
    int q   = (blk / NC) % NQ;
    int b   = blk / (NC * NQ);
    int t   = threadIdx.x;
    int lo  = q * RATOMS;

    for (int i = t; i < RATOMS * ASTRIDE; i += 256) acc[i] = 0.0f;
    const float* cb = coords + (size_t)b * NUMATOM * 3;
    for (int i = t; i < NUMATOM * 3; i += 256) lc[i] = cb[i];
    if (t < RATOMS) lsp[t] = species[b * NUMATOM + lo + t];
    if (t < NTYPE * NWAVE) { lrs[t] = rs[t]; lia[t] = -10.0f * inta[t]; }
    if (t == 0) qn = 0;
    __syncthreads();

    // Scan + compact: keep pairs whose center atom falls in [lo, lo+128)
    const int* i0row = atom_index + ((size_t)b * 2 + 0) * NPAIR + (size_t)c * CHUNK;
    for (int i = t; i < CHUNK; i += 256) {
        int a0 = i0row[i];
        if ((a0 >> 7) == q) {
            int slot = atomicAdd(&qn, 1);
            if (slot < QCAP) queue[slot] = i | ((a0 & (RATOMS - 1)) << 16);
        }
    }
    __syncthreads();
    int nkeep = qn < QCAP ? qn : QCAP;

    const int*   i1row = atom_index + ((size_t)b * 2 + 1) * NPAIR + (size_t)c * CHUNK;
    const float* shrow = shifts + ((size_t)b * NPAIR + (size_t)c * CHUNK) * 3;

    // Heavy phase: full-lane processing of compacted queue
    for (int i = t; i < nkeep; i += 256) {
        int e  = queue[i];
        int p  = e & 0xFFFF;
        int al = e >> 16;
        int a0 = lo + al;
        int a1 = i1row[p];

        float dx = lc[3 * a0 + 0] - lc[3 * a1 + 0] + shrow[3 * p + 0];
        float dy = lc[3 * a0 + 1] - lc[3 * a1 + 1] + shrow[3 * p + 1];
        float dz = lc[3 * a0 + 2] - lc[3 * a1 + 2] + shrow[3 * p + 2];

        float r   = sqrtf(dx * dx + dy * dy + dz * dz);
        float inv = 1.0f / r;
        float ux = dx * inv, uy = dy * inv, uz = dz * inv;

        int sp = lsp[al];
        float g[NWAVE];
#pragma unroll
        for (int w = 0; w < NWAVE; ++w) {
            float d = r - lrs[sp * NWAVE + w];
            g[w] = __expf(lia[sp * NWAVE + w] * d * d);
        }
        float ang[9] = { ux, uy, uz,
                         ux * ux, uy * uy, uz * uz,
                         ux * uy, ux * uz, uy * uz };

        float* ab = acc + al * ASTRIDE;
#pragma unroll
        for (int j = 0; j < 9; ++j)
#pragma unroll
            for (int w = 0; w < NWAVE; ++w)
                atomicAdd(&ab[j * NWAVE + w], ang[j] * g[w]);
    }
    __syncthreads();

    // Coalesced plane write-out (strip the bank pad)
    float* pb = part + (size_t)blk * PLANE;
    for (int i = t; i < PLANE; i += 256)
        pb[i] = acc[(i / 72) * ASTRIDE + (i % 72)];
}

// ---------------------------------------------------------------------------
// Kernel 2: one wave per atom; sum chunk planes, square, bin orders via
// shuffle butterflies, expand over types. No LDS, no block syncs.
// ---------------------------------------------------------------------------
__global__ __launch_bounds__(256) void reduce_finalize(
        const float* __restrict__ part,
        const int*   __restrict__ species,
        float*       __restrict__ out) {
    int wv = threadIdx.x >> 6;
    int l  = threadIdx.x & 63;
    int a  = blockIdx.x * 4 + wv;

    int b   = a >> 9;
    int al  = a & (NUMATOM - 1);
    int q   = al >> 7;
    int arl = al & (RATOMS - 1);

    size_t base = ((size_t)(b * NQ + q) * NC) * PLANE + (size_t)arl * 72;

    float val = 0.0f, val2 = 0.0f;
#pragma unroll
    for (int c = 0; c < NC; ++c) {
        const float* pl = part + base + (size_t)c * PLANE;
        val += pl[l];                      // elements 0..63 (j=0..7)
        if (l < 8) val2 += pl[64 + l];     // element j=8 (yz row)
    }

    float dens = val * val;
    int j = l >> 3;
    float A = (j < 3) ? dens : 0.0f;                       // order-0 contributions
    float B = (j >= 3 && j < 6) ? dens                     // diag
            : (j >= 6) ? 2.0f * dens : 0.0f;               // xy,xz doubled
    if (l < 8) B = 2.0f * val2 * val2;                     // yz doubled (j==0 lanes carry it)

#pragma unroll
    for (int m = 8; m < 64; m <<= 1) {
        A += __shfl_xor(A, m);
        B += __shfl_xor(B, m);
    }
    // all lanes now hold ord0/ord1 for w = l&7

    int sp = species[a];
    float* ob = out + (size_t)a * OUT_PER_ATOM;
    {
        int o = l, ity = o / 24, rem = o % 24, od = rem >> 3;
        ob[o] = (ity == sp && od < 2) ? (od == 0 ? A : B) : 0.0f;
    }
    if (l < 32) {
        int o = l + 64, ity = o / 24, rem = o % 24, od = rem >> 3;
        ob[o] = (ity == sp && od < 2) ? (od == 0 ? A : B) : 0.0f;
    }
}

// ---------------------------------------------------------------------------

extern "C" void kernel_launch(void* const* d_in, const int* in_sizes, int n_in,
                              void* d_out, int out_size, void* d_ws, size_t ws_size,
                              hipStream_t stream) {
    const float* coords     = (const float*)d_in[0];
    // d_in[1] = numatoms (unused by the math)
    const int*   atom_index = (const int*)  d_in[2];
    const float* shifts     = (const float*)d_in[3];
    const int*   species    = (const int*)  d_in[4];
    const float* rs         = (const float*)d_in[5];
    const float* inta       = (const float*)d_in[6];
    float*       out        = (float*)      d_out;
    float*       part       = (float*)      d_ws;  // 512 * 9216 * 4 B = 18.9 MB

    partial_accum<<<NBATCH * NQ * NC, 256, 0, stream>>>(
        coords, atom_index, shifts, species, rs, inta, part);
    reduce_finalize<<<TOTNATOM / 4, 256, 0, stream>>>(part, species, out);
}

// Round 7
// 101.923 us; speedup vs baseline: 2.3425x; 2.3425x over previous
//
#include <hip/hip_runtime.h>

// Problem constants (match reference)
#define NBATCH   16
#define NUMATOM  512
#define NEIGH    48
#define NPAIR    (NUMATOM * NEIGH)        // 24576
#define TOTNATOM (NBATCH * NUMATOM)       // 8192
#define NTYPE    4
#define NWAVE    8
#define OUT_PER_ATOM 96                    // 4 types x 3 orders x 8 waves

#define APB   8                            // atoms per block (1 per wave)
#define GPB   (NUMATOM / APB)              // 64 atom-groups per batch
#define CAP   96                           // per-atom queue capacity (max occ ~75)

// ---------------------------------------------------------------------------
// Single fused kernel. Block = 512 threads = 8 waves; wave wv owns atom
// lo+wv of batch b. Phase 1: coalesced scan of the batch's i0 list, enqueue
// matching pair indices per atom (LDS). Phase 2a: full-lane geometry for the
// queued pairs. Phase 2b: dense register accumulation (lane = (row j, wave w)),
// shuffle-butterfly order binning, direct output write.
// Rows: 0..2 = ux,uy,uz ; 3..5 = xx,yy,zz ; 6,7 = xy,xz ; row 8 (yz) carried
// by lanes 0..7 in a second accumulator. Order1 = sum(diag^2)+2*sum(offdiag^2).
// ---------------------------------------------------------------------------
__global__ __launch_bounds__(512, 4) void fused_density(
        const float* __restrict__ coords,
        const int*   __restrict__ atom_index,
        const float* __restrict__ shifts,
        const int*   __restrict__ species,
        const float* __restrict__ rs,
        const float* __restrict__ inta,
        float*       __restrict__ out) {
    __shared__ float  lc[NUMATOM * 3];     //  6144 B: batch coordinates
    __shared__ int    dq[APB * CAP];       //  3072 B: pair-index queues
    __shared__ float4 pq[APB * CAP];       // 12288 B: (u, r) descriptors
    __shared__ int    qn[APB];
    __shared__ int    lsp[APB];
    __shared__ float  lrs[NTYPE * NWAVE];
    __shared__ float  lia[NTYPE * NWAVE];

    int blk = blockIdx.x;
    int b   = blk >> 6;                    // batch
    int g   = blk & (GPB - 1);             // atom group
    int t   = threadIdx.x;
    int lo  = g * APB;                     // first local atom of this block

    const float* cb = coords + (size_t)b * NUMATOM * 3;
    for (int i = t; i < NUMATOM * 3; i += 512) lc[i] = cb[i];
    if (t < NTYPE * NWAVE) { lrs[t] = rs[t]; lia[t] = -10.0f * inta[t]; }
    if (t < APB) { qn[t] = 0; lsp[t] = species[b * NUMATOM + lo + t]; }
    __syncthreads();

    const int*   i0row = atom_index + ((size_t)b * 2 + 0) * NPAIR;
    const int*   i1row = atom_index + ((size_t)b * 2 + 1) * NPAIR;
    const float* shrow = shifts + (size_t)b * NPAIR * 3;

    // ---- Phase 1: scan + enqueue (coalesced reads; ~0.75 matches/thread)
    for (int p = t; p < NPAIR; p += 512) {
        int a0 = i0row[p];
        if ((a0 >> 3) == g) {
            int al = a0 & (APB - 1);
            int s  = atomicAdd(&qn[al], 1);
            if (s < CAP) dq[al * CAP + s] = p;
        }
    }
    __syncthreads();

    int wv = t >> 6;                       // wave id == local atom index
    int l  = t & 63;
    int c  = qn[wv]; if (c > CAP) c = CAP;

    // ---- Phase 2a: full-lane geometry into float4 queue
    int ga0 = 3 * (lo + wv);
    for (int k = l; k < c; k += 64) {
        int p  = dq[wv * CAP + k];
        int a1 = i1row[p];
        float dx = lc[ga0 + 0] - lc[3 * a1 + 0] + shrow[3 * p + 0];
        float dy = lc[ga0 + 1] - lc[3 * a1 + 1] + shrow[3 * p + 1];
        float dz = lc[ga0 + 2] - lc[3 * a1 + 2] + shrow[3 * p + 2];
        float r   = sqrtf(dx * dx + dy * dy + dz * dz);
        float inv = 1.0f / r;
        pq[wv * CAP + k] = make_float4(dx * inv, dy * inv, dz * inv, r);
    }
    __syncthreads();

    // ---- Phase 2b: dense register accumulation
    int sp = lsp[wv];
    int j  = l >> 3, w = l & 7;
    float rw = lrs[sp * NWAVE + w];
    float cw = lia[sp * NWAVE + w];

    int ia, ib;                            // ang = u[ia]*u[ib]; ib==3 -> 1.0
    if (j < 3)       { ia = j;     ib = 3;     }
    else if (j < 6)  { ia = j - 3; ib = j - 3; }
    else if (j == 6) { ia = 0;     ib = 1;     }
    else             { ia = 0;     ib = 2;     }

    const float4* q = pq + wv * CAP;
    float acc = 0.0f, acc2 = 0.0f;
    int k = 0;
    for (; k + 2 <= c; k += 2) {
        float4 v0 = q[k], v1 = q[k + 1];
        float d0 = v0.w - rw, d1 = v1.w - rw;
        float g0 = __expf(cw * d0 * d0);
        float g1 = __expf(cw * d1 * d1);
        float ua0 = (ia == 0) ? v0.x : (ia == 1) ? v0.y : v0.z;
        float ub0 = (ib == 0) ? v0.x : (ib == 1) ? v0.y : (ib == 2) ? v0.z : 1.0f;
        float ua1 = (ia == 0) ? v1.x : (ia == 1) ? v1.y : v1.z;
        float ub1 = (ib == 0) ? v1.x : (ib == 1) ? v1.y : (ib == 2) ? v1.z : 1.0f;
        acc  += ua0 * ub0 * g0 + ua1 * ub1 * g1;
        acc2 += v0.y * v0.z * g0 + v1.y * v1.z * g1;
    }
    for (; k < c; ++k) {
        float4 v = q[k];
        float d = v.w - rw;
        float gg = __expf(cw * d * d);
        float ua = (ia == 0) ? v.x : (ia == 1) ? v.y : v.z;
        float ub = (ib == 0) ? v.x : (ib == 1) ? v.y : (ib == 2) ? v.z : 1.0f;
        acc  += ua * ub * gg;
        acc2 += v.y * v.z * gg;
    }

    // ---- Order binning via shuffle butterflies
    float dens = acc * acc;
    float A = (j < 3) ? dens : 0.0f;                         // order 0
    float B = (j >= 3 && j < 6) ? dens                       // diag
            : (j >= 6) ? 2.0f * dens : 0.0f;                 // xy,xz doubled
    if (l < 8) B = 2.0f * acc2 * acc2;                       // yz doubled (j==0 lanes)

#pragma unroll
    for (int m = 8; m < 64; m <<= 1) {
        A += __shfl_xor(A, m);
        B += __shfl_xor(B, m);
    }
    // every lane now holds ord0/ord1 for its w = l&7

    // ---- Output: 96 floats for atom a (only species block nonzero)
    int a = (b << 9) + lo + wv;
    float* ob = out + (size_t)a * OUT_PER_ATOM;
    {
        int o = l, ity = o / 24, rem = o % 24, od = rem >> 3;
        ob[o] = (ity == sp && od < 2) ? (od == 0 ? A : B) : 0.0f;
    }
    if (l < 32) {
        int o = l + 64, ity = o / 24, rem = o % 24, od = rem >> 3;
        ob[o] = (ity == sp && od < 2) ? (od == 0 ? A : B) : 0.0f;
    }
}

// ---------------------------------------------------------------------------

extern "C" void kernel_launch(void* const* d_in, const int* in_sizes, int n_in,
                              void* d_out, int out_size, void* d_ws, size_t ws_size,
                              hipStream_t stream) {
    const float* coords     = (const float*)d_in[0];
    // d_in[1] = numatoms (unused by the math)
    const int*   atom_index = (const int*)  d_in[2];
    const float* shifts     = (const float*)d_in[3];
    const int*   species    = (const int*)  d_in[4];
    const float* rs         = (const float*)d_in[5];
    const float* inta       = (const float*)d_in[6];
    float*       out        = (float*)      d_out;

    fused_density<<<NBATCH * GPB, 512, 0, stream>>>(
        coords, atom_index, shifts, species, rs, inta, out);
}

// Round 9
// 100.817 us; speedup vs baseline: 2.3682x; 1.0110x over previous
//
#include <hip/hip_runtime.h>

// Problem constants (match reference)
#define NBATCH   16
#define NUMATOM  512
#define NEIGH    48
#define NPAIR    (NUMATOM * NEIGH)        // 24576
#define TOTNATOM (NBATCH * NUMATOM)       // 8192
#define NTYPE    4
#define NWAVE    8
#define OUT_PER_ATOM 96                    // 4 types x 3 orders x 8 waves

#define APB   8                            // atoms per block (1 per wave)
#define GPB   (NUMATOM / APB)              // 64 atom-groups per batch
#define CAP   96                           // per-atom queue capacity (max occ ~75)

// ---------------------------------------------------------------------------
// Single fused kernel (round-7 structure, known-good). Block = 512 threads =
// 8 waves; wave wv owns atom lo+wv of batch b. Phase 1: coalesced scalar scan
// of the batch's i0 list (unroll 4 for MLP), enqueue matching pair indices
// per atom (LDS). Phase 2a: full-lane geometry for the queued pairs.
// Phase 2b: dense register accumulation, explicit 4x unroll (4 ds_read_b128
// in flight), shuffle-butterfly order binning, direct output write.
// Rows: 0..2 = ux,uy,uz ; 3..5 = xx,yy,zz ; 6,7 = xy,xz ; row 8 (yz) carried
// by lanes 0..7 in a second accumulator. Order1 = sum(diag^2)+2*sum(offdiag^2).
// ---------------------------------------------------------------------------
__global__ __launch_bounds__(512, 4) void fused_density(
        const float* __restrict__ coords,
        const int*   __restrict__ atom_index,
        const float* __restrict__ shifts,
        const int*   __restrict__ species,
        const float* __restrict__ rs,
        const float* __restrict__ inta,
        float*       __restrict__ out) {
    __shared__ float  lc[NUMATOM * 3];     //  6144 B: batch coordinates
    __shared__ int    dq[APB * CAP];       //  3072 B: pair-index queues
    __shared__ float4 pq[APB * CAP];       // 12288 B: (u, r) descriptors
    __shared__ int    qn[APB];
    __shared__ int    lsp[APB];
    __shared__ float  lrs[NTYPE * NWAVE];
    __shared__ float  lia[NTYPE * NWAVE];

    int blk = blockIdx.x;
    int b   = blk >> 6;                    // batch
    int g   = blk & (GPB - 1);             // atom group
    int t   = threadIdx.x;
    int lo  = g * APB;                     // first local atom of this block

    const float* cb = coords + (size_t)b * NUMATOM * 3;
    for (int i = t; i < NUMATOM * 3; i += 512) lc[i] = cb[i];
    if (t < NTYPE * NWAVE) { lrs[t] = rs[t]; lia[t] = -10.0f * inta[t]; }
    if (t < APB) { qn[t] = 0; lsp[t] = species[b * NUMATOM + lo + t]; }
    __syncthreads();

    const int*   i0row = atom_index + ((size_t)b * 2 + 0) * NPAIR;
    const int*   i1row = atom_index + ((size_t)b * 2 + 1) * NPAIR;
    const float* shrow = shifts + (size_t)b * NPAIR * 3;

    // ---- Phase 1: scan + enqueue (coalesced reads; ~0.75 matches/thread)
#pragma unroll 4
    for (int p = t; p < NPAIR; p += 512) {
        int a0 = i0row[p];
        if ((a0 >> 3) == g) {
            int al = a0 & (APB - 1);
            int s  = atomicAdd(&qn[al], 1);
            if (s < CAP) dq[al * CAP + s] = p;
        }
    }
    __syncthreads();

    int wv = t >> 6;                       // wave id == local atom index
    int l  = t & 63;
    int c  = qn[wv]; if (c > CAP) c = CAP;

    // ---- Phase 2a: full-lane geometry into float4 queue
    int ga0 = 3 * (lo + wv);
    for (int k = l; k < c; k += 64) {
        int p  = dq[wv * CAP + k];
        int a1 = i1row[p];
        float dx = lc[ga0 + 0] - lc[3 * a1 + 0] + shrow[3 * p + 0];
        float dy = lc[ga0 + 1] - lc[3 * a1 + 1] + shrow[3 * p + 1];
        float dz = lc[ga0 + 2] - lc[3 * a1 + 2] + shrow[3 * p + 2];
        float r   = sqrtf(dx * dx + dy * dy + dz * dz);
        float inv = 1.0f / r;
        pq[wv * CAP + k] = make_float4(dx * inv, dy * inv, dz * inv, r);
    }
    __syncthreads();

    // ---- Phase 2b: dense register accumulation, explicit 4x unroll
    int sp = lsp[wv];
    int j  = l >> 3, w = l & 7;
    float rw = lrs[sp * NWAVE + w];
    float cw = lia[sp * NWAVE + w];

    int ia, ib;                            // ang = u[ia]*u[ib]; ib==3 -> 1.0
    if (j < 3)       { ia = j;     ib = 3;     }
    else if (j < 6)  { ia = j - 3; ib = j - 3; }
    else if (j == 6) { ia = 0;     ib = 1;     }
    else             { ia = 0;     ib = 2;     }

    const float4* q = pq + wv * CAP;
    float acc = 0.0f, acc2 = 0.0f;
    int k = 0;
    for (; k + 4 <= c; k += 4) {
        float4 v0 = q[k];
        float4 v1 = q[k + 1];
        float4 v2 = q[k + 2];
        float4 v3 = q[k + 3];
        float d0 = v0.w - rw, d1 = v1.w - rw, d2 = v2.w - rw, d3 = v3.w - rw;
        float g0 = __expf(cw * d0 * d0);
        float g1 = __expf(cw * d1 * d1);
        float g2 = __expf(cw * d2 * d2);
        float g3 = __expf(cw * d3 * d3);
        float ua0 = (ia == 0) ? v0.x : (ia == 1) ? v0.y : v0.z;
        float ub0 = (ib == 0) ? v0.x : (ib == 1) ? v0.y : (ib == 2) ? v0.z : 1.0f;
        float ua1 = (ia == 0) ? v1.x : (ia == 1) ? v1.y : v1.z;
        float ub1 = (ib == 0) ? v1.x : (ib == 1) ? v1.y : (ib == 2) ? v1.z : 1.0f;
        float ua2 = (ia == 0) ? v2.x : (ia == 1) ? v2.y : v2.z;
        float ub2 = (ib == 0) ? v2.x : (ib == 1) ? v2.y : (ib == 2) ? v2.z : 1.0f;
        float ua3 = (ia == 0) ? v3.x : (ia == 1) ? v3.y : v3.z;
        float ub3 = (ib == 0) ? v3.x : (ib == 1) ? v3.y : (ib == 2) ? v3.z : 1.0f;
        acc  += ua0 * ub0 * g0 + ua1 * ub1 * g1
              + ua2 * ub2 * g2 + ua3 * ub3 * g3;
        acc2 += v0.y * v0.z * g0 + v1.y * v1.z * g1
              + v2.y * v2.z * g2 + v3.y * v3.z * g3;
    }
    for (; k < c; ++k) {
        float4 v = q[k];
        float d = v.w - rw;
        float gg = __expf(cw * d * d);
        float ua = (ia == 0) ? v.x : (ia == 1) ? v.y : v.z;
        float ub = (ib == 0) ? v.x : (ib == 1) ? v.y : (ib == 2) ? v.z : 1.0f;
        acc  += ua * ub * gg;
        acc2 += v.y * v.z * gg;
    }

    // ---- Order binning via shuffle butterflies
    float dens = acc * acc;
    float A = (j < 3) ? dens : 0.0f;                         // order 0
    float B = (j >= 3 && j < 6) ? dens                       // diag
            : (j >= 6) ? 2.0f * dens : 0.0f;                 // xy,xz doubled
    if (l < 8) B = 2.0f * acc2 * acc2;                       // yz doubled (j==0 lanes)

#pragma unroll
    for (int m = 8; m < 64; m <<= 1) {
        A += __shfl_xor(A, m);
        B += __shfl_xor(B, m);
    }
    // every lane now holds ord0/ord1 for its w = l&7

    // ---- Output: 96 floats for atom a (only species block nonzero)
    int a = (b << 9) + lo + wv;
    float* ob = out + (size_t)a * OUT_PER_ATOM;
    {
        int o = l, ity = o / 24, rem = o % 24, od = rem >> 3;
        ob[o] = (ity == sp && od < 2) ? (od == 0 ? A : B) : 0.0f;
    }
    if (l < 32) {
        int o = l + 64, ity = o / 24, rem = o % 24, od = rem >> 3;
        ob[o] = (ity == sp && od < 2) ? (od == 0 ? A : B) : 0.0f;
    }
}

// ---------------------------------------------------------------------------

extern "C" void kernel_launch(void* const* d_in, const int* in_sizes, int n_in,
                              void* d_out, int out_size, void* d_ws, size_t ws_size,
                              hipStream_t stream) {
    const float* coords     = (const float*)d_in[0];
    // d_in[1] = numatoms (unused by the math)
    const int*   atom_index = (const int*)  d_in[2];
    const float* shifts     = (const float*)d_in[3];
    const int*   species    = (const int*)  d_in[4];
    const float* rs         = (const float*)d_in[5];
    const float* inta       = (const float*)d_in[6];
    float*       out        = (float*)      d_out;

    fused_density<<<NBATCH * GPB, 512, 0, stream>>>(
        coords, atom_index, shifts, species, rs, inta, out);
}